// Round 7
// baseline (993.741 us; speedup 1.0000x reference)
//
#include <hip/hip_runtime.h>
#include <cstdint>
#include <cstddef>

typedef short short8 __attribute__((ext_vector_type(8)));
typedef float f32x4 __attribute__((ext_vector_type(4)));
typedef unsigned long long u64x2 __attribute__((ext_vector_type(2)));

#define B_   8
#define N_   4096
#define S_   1024
#define K_   16
#define M_   131072   /* B*S*K */
#define CIN_ 64

__device__ inline float bf2f(unsigned short u) {
    unsigned int v = ((unsigned int)u) << 16;
    return __builtin_bit_cast(float, v);
}
__device__ inline unsigned short f2bf(float f) {
    unsigned int u = __builtin_bit_cast(unsigned int, f);
    unsigned int lsb = (u >> 16) & 1u;
    u += 0x7fffu + lsb;
    return (unsigned short)(u >> 16);
}
// packed 2xf32 ops (exact IEEE per component, CDNA full-rate)
__device__ inline double pk_add(double a, double b) {
    double r; asm("v_pk_add_f32 %0, %1, %2" : "=v"(r) : "v"(a), "v"(b)); return r;
}
__device__ inline double pk_mul(double a, double b) {
    double r; asm("v_pk_mul_f32 %0, %1, %2" : "=v"(r) : "v"(a), "v"(b)); return r;
}
__device__ inline unsigned cvtpk_bf16(float lo, float hi) {
    unsigned r; asm("v_cvt_pk_bf16_f32 %0, %1, %2" : "=v"(r) : "v"(lo), "v"(hi)); return r;
}
__device__ inline short8 pack8_bf16(const float* v) {
    uint4 u;
    u.x = cvtpk_bf16(v[0], v[1]); u.y = cvtpk_bf16(v[2], v[3]);
    u.z = cvtpk_bf16(v[4], v[5]); u.w = cvtpk_bf16(v[6], v[7]);
    return __builtin_bit_cast(short8, u);
}

// ---------------- FPS helper: f32 DPP max round ----------------
template<int CTRL>
__device__ inline float dpp_maxf(float x) {
    int xi = __builtin_bit_cast(int, x);
    int yi = __builtin_amdgcn_update_dpp(0, xi, CTRL, 0xF, 0xF, true);  // 0-fill ok: bd >= 0
    return fmaxf(x, __builtin_bit_cast(float, yi));
}

// ---------------- FPS (blocks 0-7) + concurrent aux prep (blocks 8-47) ----------------
// t-major point ownership (p = t*16+i); distance update uses packed-f32
// (v_pk_add/v_pk_mul) on point pairs — exact per-component IEEE, half the
// issue cost. Wave argmax: f32 DPP chain + ballot + ctz + readlane.
__global__ __launch_bounds__(256) void fps_aux_kernel(
    const float* __restrict__ xyz, float* __restrict__ outxyz,
    const float* __restrict__ fc1_w, const float* __restrict__ sc_w,
    const float* __restrict__ fc2_w, const float* __restrict__ fc3_w,
    unsigned short* __restrict__ WT1, unsigned short* __restrict__ WT2,
    unsigned short* __restrict__ WT3, float* __restrict__ sqn)
{
    __shared__ float px_s[N_], py_s[N_], pz_s[N_];   // 48 KB point mirror
    __shared__ float sOut[S_ * 3];                   // 12 KB output staging
    __shared__ __attribute__((aligned(16))) unsigned long long sK[2][4];
    int t = threadIdx.x;

    if (blockIdx.x >= 8) {
        int aux = blockIdx.x - 8;   // 0..39, each covers 10*256 flat elems
#pragma unroll
        for (int ch = 0; ch < 10; ch++) {
            int idx = (aux * 10 + ch) * 256 + t;    // 0..102399
            if (idx < 13824) {                      // WT1 (fc1): [144][96]
                int row = idx / 96, k = idx % 96;
                WT1[idx] = f2bf((k < 67 && row < 134) ? fc1_w[k * 134 + row] : 0.0f);
            } else if (idx < 26112) {               // WT1sc: [128][96]
                int j = idx - 13824;
                int row = j / 96, k = j % 96;
                WT1[13824 + j] = f2bf((k < 67) ? sc_w[k * 128 + row] : 0.0f);
            } else if (idx < 49152) {               // WT2: [144][160]
                int j = idx - 26112;
                int row = j / 160, k = j % 160;
                WT2[j] = f2bf((k < 134 && row < 134) ? fc2_w[k * 134 + row] : 0.0f);
            } else if (idx < 69632) {               // WT3: [128][160]
                int j = idx - 49152;
                int row = j / 160, k = j % 160;
                WT3[j] = f2bf((k < 134) ? fc3_w[k * 128 + row] : 0.0f);
            } else {                                // sqn: 32768 points
                int i = idx - 69632;
                float x = xyz[i * 3 + 0], y = xyz[i * 3 + 1], z = xyz[i * 3 + 2];
                sqn[i] = __fadd_rn(__fadd_rn(__fmul_rn(x, x), __fmul_rn(y, y)),
                                   __fmul_rn(z, z));
            }
        }
        return;
    }

    int b = blockIdx.x;
    const float* xb = xyz + (size_t)b * N_ * 3;
    int w = t >> 6, l = t & 63;
    double px2[8], py2[8], pz2[8];   // packed pairs: {pt 2j, pt 2j+1} per coord
    float dst[16];
    {
        // t-major load: thread t owns points t*16 .. t*16+15 (48 contiguous floats)
        float flat[48];
        const float4* xb4 = (const float4*)xb + t * 12;
#pragma unroll
        for (int j = 0; j < 12; j++) {
            float4 v = xb4[j];
            flat[j * 4 + 0] = v.x; flat[j * 4 + 1] = v.y;
            flat[j * 4 + 2] = v.z; flat[j * 4 + 3] = v.w;
        }
#pragma unroll
        for (int i = 0; i < 16; i++) {
            int p = t * 16 + i;
            px_s[p] = flat[i * 3 + 0];
            py_s[p] = flat[i * 3 + 1];
            pz_s[p] = flat[i * 3 + 2];
            dst[i] = 1e10f;
        }
#pragma unroll
        for (int j = 0; j < 8; j++) {
            float2 X = make_float2(flat[6 * j + 0], flat[6 * j + 3]);
            float2 Y = make_float2(flat[6 * j + 1], flat[6 * j + 4]);
            float2 Z = make_float2(flat[6 * j + 2], flat[6 * j + 5]);
            px2[j] = __builtin_bit_cast(double, X);
            py2[j] = __builtin_bit_cast(double, Y);
            pz2[j] = __builtin_bit_cast(double, Z);
            asm volatile("" : "+v"(px2[j]), "+v"(py2[j]), "+v"(pz2[j]));  // pin pairs
        }
    }
    __syncthreads();
    float cx = px_s[0], cy = py_s[0], cz = pz_s[0];  // far = 0 deterministic start
    for (int s = 0; s < S_; s++) {
        if (t == 0) { sOut[s * 3 + 0] = cx; sOut[s * 3 + 1] = cy; sOut[s * 3 + 2] = cz; }
        if (s == S_ - 1) break;
        // negated-centroid pairs (p + (-c) == p - c exactly)
        double ncx2 = __builtin_bit_cast(double, make_float2(-cx, -cx));
        double ncy2 = __builtin_bit_cast(double, make_float2(-cy, -cy));
        double ncz2 = __builtin_bit_cast(double, make_float2(-cz, -cz));
        float bd = -1.0f; int bi = 0;
#pragma unroll
        for (int j = 0; j < 8; j++) {
            // exact ref semantics per component: sub, mul, (xx+yy)+zz, no FMA
            double dx2 = pk_add(px2[j], ncx2);
            double dy2 = pk_add(py2[j], ncy2);
            double dz2 = pk_add(pz2[j], ncz2);
            double d2  = pk_add(pk_add(pk_mul(dx2, dx2), pk_mul(dy2, dy2)),
                                pk_mul(dz2, dz2));
            float2 df = __builtin_bit_cast(float2, d2);
            float nd0 = fminf(dst[2 * j + 0], df.x);
            dst[2 * j + 0] = nd0;
            if (nd0 > bd) bi = 2 * j + 0;     // strict >: tie keeps lower i (= lower p)
            bd = fmaxf(bd, nd0);
            float nd1 = fminf(dst[2 * j + 1], df.y);
            dst[2 * j + 1] = nd1;
            if (nd1 > bd) bi = 2 * j + 1;
            bd = fmaxf(bd, nd1);
        }
        // wave max via f32-only DPP chain (lane 63 holds wave max)
        float m = bd;
        m = dpp_maxf<0xB1>(m);    // lane ^ 1
        m = dpp_maxf<0x4E>(m);    // lane ^ 2
        m = dpp_maxf<0x141>(m);   // row_half_mirror (8-group)
        m = dpp_maxf<0x140>(m);   // row_mirror (16-group)
        m = dpp_maxf<0x142>(m);   // row_bcast15 -> 32-group partial
        m = dpp_maxf<0x143>(m);   // row_bcast31 -> lane 63 = wave max
        float bw = __builtin_bit_cast(float,
                       __builtin_amdgcn_readlane(__builtin_bit_cast(int, m), 63));
        unsigned long long msk = __ballot(bd == bw);
        int wl  = (int)__builtin_ctzll(msk);                 // lowest lane = lowest p (t-major)
        int wbi = __builtin_amdgcn_readlane(bi, wl);
        int pw  = (w * 64 + wl) * 16 + wbi;                  // winner point of this wave
        unsigned long long key =
            ((unsigned long long)__builtin_bit_cast(unsigned, bw) << 32) |
            (unsigned long long)(unsigned)(4095 - pw);       // tie -> lowest p
        int par = s & 1;
        if (l == 0) sK[par][w] = key;
        __syncthreads();
        u64x2 kA = *(u64x2*)&sK[par][0];
        u64x2 kB = *(u64x2*)&sK[par][2];
        unsigned long long ka = kA[0] > kA[1] ? kA[0] : kA[1];
        unsigned long long kb = kB[0] > kB[1] ? kB[0] : kB[1];
        unsigned long long g  = ka > kb ? ka : kb;
        int p = 4095 - (int)(g & 0xFFFu);
        cx = px_s[p]; cy = py_s[p]; cz = pz_s[p];    // LDS broadcast
    }
    __syncthreads();
    float* ob = outxyz + (size_t)b * S_ * 3;
    for (int i = t; i < S_ * 3; i += 256) ob[i] = sOut[i];
}

// ---------------- kNN (one wave per query) + fused X build ----------------
__global__ __launch_bounds__(256) void knn_build(const float* __restrict__ xyz,
                                                 const float* __restrict__ sqn,
                                                 const float* __restrict__ newxyz,
                                                 const float* __restrict__ pts,
                                                 unsigned short* __restrict__ X)
{
    __shared__ int sNbr[4][16];
    int w = threadIdx.x >> 6, l = threadIdx.x & 63;
    int q = blockIdx.x * 4 + w;          // 0..8191
    int b = q >> 10;
    const float* xb = xyz + (size_t)b * N_ * 3;
    const float* sb = sqn + (size_t)b * N_;
    float qx = newxyz[(size_t)q * 3 + 0];
    float qy = newxyz[(size_t)q * 3 + 1];
    float qz = newxyz[(size_t)q * 3 + 2];
    float sa = __fadd_rn(__fadd_rn(__fmul_rn(qx, qx), __fmul_rn(qy, qy)), __fmul_rn(qz, qz));

    float d16[16]; int i16[16];
#pragma unroll
    for (int j = 0; j < 16; j++) { d16[j] = 3.0e38f; i16[j] = -1; }
    // d16 kept descending: d16[0] = current worst, d16[15] = best
    for (int i = 0; i < N_ / 64; i++) {
        int n = i * 64 + l;
        float bx = xb[n * 3 + 0], by = xb[n * 3 + 1], bz = xb[n * 3 + 2];
        float dot = __fmaf_rn(qz, bz, __fmaf_rn(qy, by, __fmul_rn(qx, bx)));
        float d = __fsub_rn(__fadd_rn(sa, sb[n]), __fmul_rn(2.0f, dot));
        if (d < d16[0]) {   // strict: equal keeps older (lower) index, matches stable top_k
            d16[0] = d; i16[0] = n;
#pragma unroll
            for (int j = 0; j < 15; j++) {
                if (d16[j] < d16[j + 1]) {
                    float td = d16[j]; d16[j] = d16[j + 1]; d16[j + 1] = td;
                    int   ti = i16[j]; i16[j] = i16[j + 1]; i16[j + 1] = ti;
                }
            }
        }
    }
#pragma unroll
    for (int r = 0; r < 16; r++) {
        float cd = d16[15]; int cn = i16[15];
#pragma unroll
        for (int off = 1; off < 64; off <<= 1) {
            float od = __shfl_xor(cd, off);
            int   on = __shfl_xor(cn, off);
            if (od < cd || (od == cd && on < cn)) { cd = od; cn = on; }
        }
        if (l == 0) sNbr[w][r] = cn;
        if (i16[15] == cn) {   // winner pops (n unique across lanes)
#pragma unroll
            for (int j = 15; j >= 1; j--) { d16[j] = d16[j - 1]; i16[j] = i16[j - 1]; }
            d16[0] = 3.0e38f; i16[0] = -1;
        }
    }
    __syncthreads();
    // build X rows q*16..q*16+15: 4 lanes per row, 24 cols each
    int row = l >> 2, seg = l & 3;
    int n = sNbr[w][row];
    const float* pr = pts + ((size_t)b * N_ + n) * CIN_;
    const float* xr = xyz + ((size_t)b * N_ + n) * 3;
    float v[24];
#pragma unroll
    for (int e = 0; e < 24; e++) {
        int c = seg * 24 + e;
        float val;
        if (c == 0)      val = xr[0] - qx;
        else if (c == 1) val = xr[1] - qy;
        else if (c == 2) val = xr[2] - qz;
        else if (c < 67) val = pr[c - 3];
        else             val = 0.0f;
        v[e] = val;
    }
    short8 s0 = pack8_bf16(v), s1 = pack8_bf16(v + 8), s2 = pack8_bf16(v + 16);
    unsigned short* xp = X + ((size_t)q * 16 + row) * 96 + seg * 24;
    *(short8*)xp = s0;
    *(short8*)(xp + 8) = s1;
    *(short8*)(xp + 16) = s2;
}

// ---------------- MFMA GEMM core: fused BN-stats, optional BN+ReLU staging,
//                  conflict-padded LDS, coalesced epilogue via LDS transpose ----
template<int KPAD, int NF, bool BNST>
__device__ __forceinline__ void gemm_core(
    const unsigned short* __restrict__ A, const unsigned short* __restrict__ Wt,
    unsigned short* __restrict__ Zo, float* __restrict__ sum, float* __restrict__ sq,
    int nreal, const float* __restrict__ ps, const float* __restrict__ pq,
    const float* __restrict__ pg, const float* __restrict__ pb,
    int r0, unsigned short* sBuf, float* sSt, float* sAC, int t)
{
    constexpr int AST = KPAD + 8;        // padded stride: 2-way-max bank aliasing
    for (int i = t; i < NF * 32; i += 256) sSt[i] = 0.0f;
    if (BNST) {
        // per-block BN finalize from global sums (deterministic, identical per block)
        if (t < 160) {
            float a = 0.f, c = 0.f;
            if (t < 134) {
                const float inv = 1.0f / (float)M_;
                float m = ps[t] * inv;
                float var = pq[t] * inv - m * m;
                a = pg[t] * rsqrtf(var + 1e-5f);
                c = pb[t] - a * m;
            }
            sAC[2 * t] = a; sAC[2 * t + 1] = c;
        }
        __syncthreads();
        // stage: relu(a*z+c) from Zin[M][144] -> sBuf[128][AST] (cols>=134 -> 0)
#pragma unroll
        for (int c8 = 0; c8 < 10; c8++) {
            int chunk = c8 * 256 + t;                  // 2560 = 128 rows * 20 chunks
            int row = chunk / 20, col0 = (chunk % 20) * 8;
            short8 hv = {0, 0, 0, 0, 0, 0, 0, 0};
            if (col0 < 144) {
                short8 zv = *(const short8*)(A + (size_t)(r0 + row) * 144 + col0);
                float tmp[8];
#pragma unroll
                for (int e = 0; e < 8; e++) {
                    float2 ac = *(float2*)&sAC[2 * (col0 + e)];
                    tmp[e] = fmaxf(ac.x * bf2f((unsigned short)zv[e]) + ac.y, 0.0f);
                }
                hv = pack8_bf16(tmp);
            }
            *(short8*)(sBuf + row * AST + col0) = hv;
        }
    } else {
#pragma unroll
        for (int c8 = 0; c8 < (128 * KPAD / 8) / 256; c8++) {
            int chunk = c8 * 256 + t;
            int row = chunk / (KPAD / 8), col0 = (chunk % (KPAD / 8)) * 8;
            *(short8*)(sBuf + row * AST + col0) =
                *(const short8*)(A + (size_t)(r0 + row) * KPAD + col0);
        }
    }
    __syncthreads();
    int w = t >> 6, l = t & 63, lhi = l >> 4, llo = l & 15;
    f32x4 acc[2][NF];
#pragma unroll
    for (int m = 0; m < 2; m++)
#pragma unroll
        for (int n = 0; n < NF; n++) acc[m][n] = (f32x4){0.f, 0.f, 0.f, 0.f};
#pragma unroll
    for (int ks = 0; ks < KPAD / 32; ks++) {
        short8 bfr[NF];
#pragma unroll
        for (int n = 0; n < NF; n++)
            bfr[n] = *(const short8*)(Wt + (size_t)(n * 16 + llo) * KPAD + ks * 32 + lhi * 8);
#pragma unroll
        for (int m = 0; m < 2; m++) {
            short8 afr = *(const short8*)(sBuf + (w * 32 + m * 16 + llo) * AST + ks * 32 + lhi * 8);
#pragma unroll
            for (int n = 0; n < NF; n++)
                acc[m][n] = __builtin_amdgcn_mfma_f32_16x16x32_bf16(afr, bfr[n], acc[m][n], 0, 0, 0);
        }
    }
    __syncthreads();   // all waves done reading A-tile; reuse sBuf as output tile
    constexpr int OST = NF * 16 + 8;
#pragma unroll
    for (int n = 0; n < NF; n++) {
        int c = n * 16 + llo;
        float ss = 0.f, sqv = 0.f;
#pragma unroll
        for (int m = 0; m < 2; m++) {
#pragma unroll
            for (int j = 0; j < 4; j++) {
                float v = acc[m][n][j];
                int row = w * 32 + m * 16 + lhi * 4 + j;
                sBuf[row * OST + c] = f2bf(v);
                ss += v; sqv += v * v;
            }
        }
        ss += __shfl_xor(ss, 16); ss += __shfl_xor(ss, 32);
        sqv += __shfl_xor(sqv, 16); sqv += __shfl_xor(sqv, 32);
        if (l < 16) { atomicAdd(&sSt[c * 2], ss); atomicAdd(&sSt[c * 2 + 1], sqv); }
    }
    __syncthreads();
    // coalesced row-major store of the 128 x NF*16 tile
#pragma unroll
    for (int c8 = 0; c8 < NF; c8++) {
        int chunk = c8 * 256 + t;                  // 128 * NF*2 chunks
        int row = chunk / (NF * 2), cc = chunk % (NF * 2);
        *(short8*)(Zo + (size_t)(r0 + row) * (NF * 16) + cc * 8) =
            *(const short8*)(sBuf + row * OST + cc * 8);
    }
    for (int c = t; c < NF * 16; c += 256) {
        if (c < nreal) {
            atomicAdd(&sum[c], sSt[c * 2]);
            atomicAdd(&sq[c], sSt[c * 2 + 1]);
        }
    }
}

// gemm1 + shortcut gemm fused in one dispatch (both read X)
__global__ __launch_bounds__(256) void gemm1_fused(
    const unsigned short* __restrict__ X, const unsigned short* __restrict__ WT1,
    unsigned short* __restrict__ Z1, unsigned short* __restrict__ ZSC,
    float* s1, float* q1, float* ssc, float* qsc)
{
    __shared__ unsigned short sBuf[21504];
    __shared__ float sSt[288];
    int t = threadIdx.x;
    if (blockIdx.x < 1024)
        gemm_core<96, 9, false>(X, WT1, Z1, s1, q1, 134,
                                nullptr, nullptr, nullptr, nullptr,
                                blockIdx.x * 128, sBuf, sSt, nullptr, t);
    else
        gemm_core<96, 8, false>(X, WT1 + 13824, ZSC, ssc, qsc, 128,
                                nullptr, nullptr, nullptr, nullptr,
                                (blockIdx.x - 1024) * 128, sBuf, sSt, nullptr, t);
}

// layer2: stages relu(bn1(Z1)) inline
__global__ __launch_bounds__(256) void gemm_l2(
    const unsigned short* __restrict__ Zin, const unsigned short* __restrict__ WT,
    unsigned short* __restrict__ Zout, float* sum, float* sq,
    const float* ps, const float* pq, const float* pg, const float* pb)
{
    __shared__ unsigned short sBuf[21504];
    __shared__ float sSt[288];
    __shared__ float sAC[320];
    gemm_core<160, 9, true>(Zin, WT, Zout, sum, sq, 134, ps, pq, pg, pb,
                            blockIdx.x * 128, sBuf, sSt, sAC, threadIdx.x);
}

// layer3: stages relu(bn2(Z2)) inline
__global__ __launch_bounds__(256) void gemm_l3(
    const unsigned short* __restrict__ Zin, const unsigned short* __restrict__ WT,
    unsigned short* __restrict__ Zout, float* sum, float* sq,
    const float* ps, const float* pq, const float* pg, const float* pb)
{
    __shared__ unsigned short sBuf[21504];
    __shared__ float sSt[288];
    __shared__ float sAC[320];
    gemm_core<160, 8, true>(Zin, WT, Zout, sum, sq, 128, ps, pq, pg, pb,
                            blockIdx.x * 128, sBuf, sSt, sAC, threadIdx.x);
}

// ---------------- final: bn3+bnsc (finalize fused), relu, max over K ----------------
__global__ __launch_bounds__(256) void final_kernel(
    const unsigned short* __restrict__ Z3, const unsigned short* __restrict__ ZSC,
    const float* __restrict__ sum3, const float* __restrict__ sq3,
    const float* __restrict__ g3, const float* __restrict__ b3,
    const float* __restrict__ sumsc, const float* __restrict__ sqsc,
    const float* __restrict__ gsc, const float* __restrict__ bsc,
    float* __restrict__ out)
{
    __shared__ float sF[512];   // per-ch {a3,c3,asc,csc}
    int t = threadIdx.x;
    if (t < 128) {
        const float inv = 1.0f / (float)M_;
        float m3 = sum3[t] * inv, v3 = sq3[t] * inv - m3 * m3;
        float a3 = g3[t] * rsqrtf(v3 + 1e-5f), c3 = b3[t] - a3 * m3;
        float ms = sumsc[t] * inv, vs = sqsc[t] * inv - ms * ms;
        float as = gsc[t] * rsqrtf(vs + 1e-5f), cs = bsc[t] - as * ms;
        sF[t * 4 + 0] = a3; sF[t * 4 + 1] = c3; sF[t * 4 + 2] = as; sF[t * 4 + 3] = cs;
    }
    __syncthreads();
    int tid = blockIdx.x * 256 + t;   // 8192*16 = 131072 exactly
    int bs = tid >> 4, ch0 = (tid & 15) * 8;
    float A3[8], C3[8], AS[8], CS[8], mx[8];
#pragma unroll
    for (int e = 0; e < 8; e++) {
        f32x4 f = *(f32x4*)&sF[(ch0 + e) * 4];
        A3[e] = f[0]; C3[e] = f[1]; AS[e] = f[2]; CS[e] = f[3];
        mx[e] = 0.0f;
    }
    const unsigned short* z3p = Z3 + (size_t)bs * 16 * 128 + ch0;
    const unsigned short* zsp = ZSC + (size_t)bs * 16 * 128 + ch0;
#pragma unroll
    for (int k = 0; k < 16; k++) {
        short8 z3 = *(const short8*)(z3p + (size_t)k * 128);
        short8 zs = *(const short8*)(zsp + (size_t)k * 128);
#pragma unroll
        for (int e = 0; e < 8; e++) {
            float y = fmaxf(A3[e] * bf2f((unsigned short)z3[e]) + C3[e]
                            + AS[e] * bf2f((unsigned short)zs[e]) + CS[e], 0.0f);
            mx[e] = fmaxf(mx[e], y);
        }
    }
    float* op = out + 24576 + (size_t)bs * 128 + ch0;
#pragma unroll
    for (int e = 0; e < 8; e++) op[e] = mx[e];
}

// ---------------- workspace layout (bytes) ----------------
#define WS_STATS 0           /* 1056 floats */
#define WS_WT1   8192        /* 26112 bf16 */
#define WS_WT2   61440       /* 23040 bf16 */
#define WS_WT3   108544      /* 20480 bf16 */
#define WS_SQN   149760      /* 32768 f32 */
#define WS_X     281088      /* M*96 bf16 */
#define WS_Z1    25447424    /* M*144 bf16 (reused as Z3 [M][128]) */
#define WS_ZSC   63196416    /* M*128 bf16 */
#define WS_Z2    96751104    /* M*144 bf16; end ~134.5 MB */

extern "C" void kernel_launch(void* const* d_in, const int* in_sizes, int n_in,
                              void* d_out, int out_size, void* d_ws, size_t ws_size,
                              hipStream_t stream)
{
    const float* xyz    = (const float*)d_in[0];
    const float* pts    = (const float*)d_in[1];
    const float* fc1_w  = (const float*)d_in[2];
    const float* bn1_g  = (const float*)d_in[4];
    const float* bn1_b  = (const float*)d_in[5];
    const float* fc2_w  = (const float*)d_in[6];
    const float* bn2_g  = (const float*)d_in[8];
    const float* bn2_b  = (const float*)d_in[9];
    const float* fc3_w  = (const float*)d_in[10];
    const float* bn3_g  = (const float*)d_in[12];
    const float* bn3_b  = (const float*)d_in[13];
    const float* sc_w   = (const float*)d_in[14];
    const float* scbn_g = (const float*)d_in[16];
    const float* scbn_b = (const float*)d_in[17];

    char* ws = (char*)d_ws;
    float* st = (float*)(ws + WS_STATS);
    float* bn1_sum = st + 0,    *bn1_sq = st + 136;
    float* bnsc_sum = st + 272, *bnsc_sq = st + 400;
    float* bn2_sum = st + 528,  *bn2_sq = st + 664;
    float* bn3_sum = st + 800,  *bn3_sq = st + 928;

    unsigned short* WT1 = (unsigned short*)(ws + WS_WT1);
    unsigned short* WT2 = (unsigned short*)(ws + WS_WT2);
    unsigned short* WT3 = (unsigned short*)(ws + WS_WT3);
    float* SQN = (float*)(ws + WS_SQN);
    unsigned short* X   = (unsigned short*)(ws + WS_X);
    unsigned short* Z1  = (unsigned short*)(ws + WS_Z1);
    unsigned short* ZSC = (unsigned short*)(ws + WS_ZSC);
    unsigned short* Z2  = (unsigned short*)(ws + WS_Z2);
    unsigned short* Z3  = Z1;   // Z1 dead after gemm_l2
    float* out = (float*)d_out;

    hipMemsetAsync(ws + WS_STATS, 0, 1056 * 4, stream);

    fps_aux_kernel<<<48, 256, 0, stream>>>(xyz, out, fc1_w, sc_w, fc2_w, fc3_w,
                                           WT1, WT2, WT3, SQN);
    knn_build<<<2048, 256, 0, stream>>>(xyz, SQN, out, pts, X);

    gemm1_fused<<<2048, 256, 0, stream>>>(X, WT1, Z1, ZSC,
                                          bn1_sum, bn1_sq, bnsc_sum, bnsc_sq);
    gemm_l2<<<1024, 256, 0, stream>>>(Z1, WT2, Z2, bn2_sum, bn2_sq,
                                      bn1_sum, bn1_sq, bn1_g, bn1_b);
    gemm_l3<<<1024, 256, 0, stream>>>(Z2, WT3, Z3, bn3_sum, bn3_sq,
                                      bn2_sum, bn2_sq, bn2_g, bn2_b);

    final_kernel<<<512, 256, 0, stream>>>(Z3, ZSC, bn3_sum, bn3_sq, bn3_g, bn3_b,
                                          bnsc_sum, bnsc_sq, scbn_g, scbn_b, out);
}

// Round 8
// 959.675 us; speedup vs baseline: 1.0355x; 1.0355x over previous
//
#include <hip/hip_runtime.h>
#include <cstdint>
#include <cstddef>

typedef short short8 __attribute__((ext_vector_type(8)));
typedef float f32x4 __attribute__((ext_vector_type(4)));
typedef unsigned long long u64x2 __attribute__((ext_vector_type(2)));

#define B_   8
#define N_   4096
#define S_   1024
#define K_   16
#define M_   131072   /* B*S*K */
#define CIN_ 64

__device__ inline float bf2f(unsigned short u) {
    unsigned int v = ((unsigned int)u) << 16;
    return __builtin_bit_cast(float, v);
}
__device__ inline unsigned short f2bf(float f) {
    unsigned int u = __builtin_bit_cast(unsigned int, f);
    unsigned int lsb = (u >> 16) & 1u;
    u += 0x7fffu + lsb;
    return (unsigned short)(u >> 16);
}
__device__ inline unsigned cvtpk_bf16(float lo, float hi) {
    unsigned r; asm("v_cvt_pk_bf16_f32 %0, %1, %2" : "=v"(r) : "v"(lo), "v"(hi)); return r;
}
__device__ inline short8 pack8_bf16(const float* v) {
    uint4 u;
    u.x = cvtpk_bf16(v[0], v[1]); u.y = cvtpk_bf16(v[2], v[3]);
    u.z = cvtpk_bf16(v[4], v[5]); u.w = cvtpk_bf16(v[6], v[7]);
    return __builtin_bit_cast(short8, u);
}

// ---------------- FPS helper: f32 DPP max round ----------------
template<int CTRL>
__device__ inline float dpp_maxf(float x) {
    int xi = __builtin_bit_cast(int, x);
    int yi = __builtin_amdgcn_update_dpp(0, xi, CTRL, 0xF, 0xF, true);  // 0-fill ok: bd >= 0
    return fmaxf(x, __builtin_bit_cast(float, yi));
}

// ---------------- shared MFMA GEMM core (leading barrier protects smem reuse) ----
template<int KPAD, int NF, bool BNST>
__device__ __forceinline__ void gemm_core(
    const unsigned short* __restrict__ A, const unsigned short* __restrict__ Wt,
    unsigned short* __restrict__ Zo, float* __restrict__ sum, float* __restrict__ sq,
    int nreal, const float* __restrict__ ps, const float* __restrict__ pq,
    const float* __restrict__ pg, const float* __restrict__ pb,
    int r0, unsigned short* sBuf, float* sSt, float* sAC, int t)
{
    __syncthreads();                      // protect smem vs previous invocation
    constexpr int AST = KPAD + 8;         // padded stride
    for (int i = t; i < NF * 32; i += 256) sSt[i] = 0.0f;
    if (BNST) {
        if (t < 160) {
            float a = 0.f, c = 0.f;
            if (t < 134) {
                const float inv = 1.0f / (float)M_;
                float m = ps[t] * inv;
                float var = pq[t] * inv - m * m;
                a = pg[t] * rsqrtf(var + 1e-5f);
                c = pb[t] - a * m;
            }
            sAC[2 * t] = a; sAC[2 * t + 1] = c;
        }
        __syncthreads();
#pragma unroll
        for (int c8 = 0; c8 < 10; c8++) {
            int chunk = c8 * 256 + t;
            int row = chunk / 20, col0 = (chunk % 20) * 8;
            short8 hv = {0, 0, 0, 0, 0, 0, 0, 0};
            if (col0 < 144) {
                short8 zv = *(const short8*)(A + (size_t)(r0 + row) * 144 + col0);
                float tmp[8];
#pragma unroll
                for (int e = 0; e < 8; e++) {
                    float2 ac = *(float2*)&sAC[2 * (col0 + e)];
                    tmp[e] = fmaxf(ac.x * bf2f((unsigned short)zv[e]) + ac.y, 0.0f);
                }
                hv = pack8_bf16(tmp);
            }
            *(short8*)(sBuf + row * AST + col0) = hv;
        }
    } else {
#pragma unroll
        for (int c8 = 0; c8 < (128 * KPAD / 8) / 256; c8++) {
            int chunk = c8 * 256 + t;
            int row = chunk / (KPAD / 8), col0 = (chunk % (KPAD / 8)) * 8;
            *(short8*)(sBuf + row * AST + col0) =
                *(const short8*)(A + (size_t)(r0 + row) * KPAD + col0);
        }
    }
    __syncthreads();
    int w = t >> 6, l = t & 63, lhi = l >> 4, llo = l & 15;
    f32x4 acc[2][NF];
#pragma unroll
    for (int m = 0; m < 2; m++)
#pragma unroll
        for (int n = 0; n < NF; n++) acc[m][n] = (f32x4){0.f, 0.f, 0.f, 0.f};
#pragma unroll
    for (int ks = 0; ks < KPAD / 32; ks++) {
        short8 bfr[NF];
#pragma unroll
        for (int n = 0; n < NF; n++)
            bfr[n] = *(const short8*)(Wt + (size_t)(n * 16 + llo) * KPAD + ks * 32 + lhi * 8);
#pragma unroll
        for (int m = 0; m < 2; m++) {
            short8 afr = *(const short8*)(sBuf + (w * 32 + m * 16 + llo) * AST + ks * 32 + lhi * 8);
#pragma unroll
            for (int n = 0; n < NF; n++)
                acc[m][n] = __builtin_amdgcn_mfma_f32_16x16x32_bf16(afr, bfr[n], acc[m][n], 0, 0, 0);
        }
    }
    __syncthreads();   // A-tile reads done; reuse sBuf as output tile
    constexpr int OST = NF * 16 + 8;
#pragma unroll
    for (int n = 0; n < NF; n++) {
        int c = n * 16 + llo;
        float ss = 0.f, sqv = 0.f;
#pragma unroll
        for (int m = 0; m < 2; m++) {
#pragma unroll
            for (int j = 0; j < 4; j++) {
                float v = acc[m][n][j];
                int row = w * 32 + m * 16 + lhi * 4 + j;
                sBuf[row * OST + c] = f2bf(v);
                ss += v; sqv += v * v;
            }
        }
        ss += __shfl_xor(ss, 16); ss += __shfl_xor(ss, 32);
        sqv += __shfl_xor(sqv, 16); sqv += __shfl_xor(sqv, 32);
        if (l < 16) { atomicAdd(&sSt[c * 2], ss); atomicAdd(&sSt[c * 2 + 1], sqv); }
    }
    __syncthreads();
#pragma unroll
    for (int c8 = 0; c8 < NF; c8++) {
        int chunk = c8 * 256 + t;
        int row = chunk / (NF * 2), cc = chunk % (NF * 2);
        *(short8*)(Zo + (size_t)(r0 + row) * (NF * 16) + cc * 8) =
            *(const short8*)(sBuf + row * OST + cc * 8);
    }
    for (int c = t; c < NF * 16; c += 256) {
        if (c < nreal) {
            atomicAdd(&sum[c], sSt[c * 2]);
            atomicAdd(&sq[c], sSt[c * 2 + 1]);
        }
    }
}

// ---------------- device-wide barrier (requires co-residency: cooperative launch) ----
__device__ inline void gridbar(int* cnt, int* gen, int nblk, int t)
{
    __syncthreads();
    __threadfence();
    if (t == 0) {
        int g = __hip_atomic_load(gen, __ATOMIC_RELAXED, __HIP_MEMORY_SCOPE_AGENT);
        if (__hip_atomic_fetch_add(cnt, 1, __ATOMIC_ACQ_REL, __HIP_MEMORY_SCOPE_AGENT) == nblk - 1) {
            __hip_atomic_store(cnt, 0, __ATOMIC_RELAXED, __HIP_MEMORY_SCOPE_AGENT);
            __hip_atomic_store(gen, g + 1, __ATOMIC_RELEASE, __HIP_MEMORY_SCOPE_AGENT);
        } else {
            while (__hip_atomic_load(gen, __ATOMIC_ACQUIRE, __HIP_MEMORY_SCOPE_AGENT) == g)
                __builtin_amdgcn_s_sleep(8);
        }
    }
    __syncthreads();
    __threadfence();
}

struct MegaArgs {
    const float *xyz, *pts, *fc1_w, *sc_w, *fc2_w, *fc3_w;
    const float *bn1_g, *bn1_b, *bn2_g, *bn2_b, *bn3_g, *bn3_b, *scbn_g, *scbn_b;
    unsigned short *WT1, *WT2, *WT3;
    float *SQN;
    unsigned short *X, *Z1, *ZSC, *Z2;
    float *st; int *wm; int *bar_cnt; int *bar_gen;
    float *out;
    int workers;
};

// =====================================================================
// MEGA: blocks 0-7 = FPS (R6 core + chunked centroid publish);
// workers = WT prep + watermark-gated kNN+X (hidden under FPS);
// then grid barriers + g1/g2/g3/final phases. Single dispatch.
// =====================================================================
__global__ __launch_bounds__(256) void mega(MegaArgs A)
{
    __shared__ __attribute__((aligned(16))) char smem[61952];
    int t = threadIdx.x;
    int bid = blockIdx.x;
    int nblk = gridDim.x;

    float* st = A.st;
    float* bn1_sum = st + 0,    *bn1_sq = st + 136;
    float* bnsc_sum = st + 272, *bnsc_sq = st + 400;
    float* bn2_sum = st + 528,  *bn2_sq = st + 664;
    float* bn3_sum = st + 800,  *bn3_sq = st + 928;

    if (bid < 8) {
        // ---------------- FPS (R6 core) ----------------
        float* px_s = (float*)smem;
        float* py_s = px_s + 4096;
        float* pz_s = px_s + 8192;
        float* sOut = (float*)(smem + 49152);
        unsigned long long* sK = (unsigned long long*)(smem + 61440);  // [2][4]
        int b = bid;
        const float* xb = A.xyz + (size_t)b * N_ * 3;
        float* ob = A.out + (size_t)b * S_ * 3;
        int w = t >> 6, l = t & 63;
        float px[16], py[16], pz[16], dst[16];
        {
            float flat[48];
            const float4* xb4 = (const float4*)xb + t * 12;
#pragma unroll
            for (int j = 0; j < 12; j++) {
                float4 v = xb4[j];
                flat[j * 4 + 0] = v.x; flat[j * 4 + 1] = v.y;
                flat[j * 4 + 2] = v.z; flat[j * 4 + 3] = v.w;
            }
#pragma unroll
            for (int i = 0; i < 16; i++) {
                int p = t * 16 + i;
                px[i] = flat[i * 3 + 0];
                py[i] = flat[i * 3 + 1];
                pz[i] = flat[i * 3 + 2];
                dst[i] = 1e10f;
                px_s[p] = px[i]; py_s[p] = py[i]; pz_s[p] = pz[i];
                asm volatile("" : "+v"(px[i]), "+v"(py[i]), "+v"(pz[i]));
            }
        }
        __syncthreads();
        float cx = px_s[0], cy = py_s[0], cz = pz_s[0];
        for (int s = 0; s < S_; s++) {
            if (t == 0) { sOut[s * 3 + 0] = cx; sOut[s * 3 + 1] = cy; sOut[s * 3 + 2] = cz; }
            // publish a 64-centroid chunk (batched stores; watermark release)
            if ((s & 63) == 63 && w == 0) {
                int base = (s - 63) * 3;   // 192 floats
                if (l < 48) {
                    float4 v = *(float4*)&sOut[base + l * 4];
                    *(float4*)&ob[base + l * 4] = v;
                }
                __threadfence();
                if (t == 0)
                    __hip_atomic_store(A.wm + b * 16, s + 1, __ATOMIC_RELEASE,
                                       __HIP_MEMORY_SCOPE_AGENT);
            }
            if (s == S_ - 1) break;
            float bd = -1.0f; int bi = 0;
#pragma unroll
            for (int i = 0; i < 16; i++) {
                // exact ref semantics: plain mul/add, no FMA contraction
                float dx = __fsub_rn(px[i], cx);
                float dy = __fsub_rn(py[i], cy);
                float dz = __fsub_rn(pz[i], cz);
                float d  = __fadd_rn(__fadd_rn(__fmul_rn(dx, dx), __fmul_rn(dy, dy)),
                                     __fmul_rn(dz, dz));
                float nd = fminf(dst[i], d);
                dst[i] = nd;
                if (nd > bd) bi = i;     // strict >: tie keeps lower i (= lower p)
                bd = fmaxf(bd, nd);
            }
            float m = bd;
            m = dpp_maxf<0xB1>(m);    // lane ^ 1
            m = dpp_maxf<0x4E>(m);    // lane ^ 2
            m = dpp_maxf<0x141>(m);   // row_half_mirror
            m = dpp_maxf<0x140>(m);   // row_mirror
            m = dpp_maxf<0x142>(m);   // row_bcast15
            m = dpp_maxf<0x143>(m);   // row_bcast31 -> lane 63 = wave max
            float bw = __builtin_bit_cast(float,
                           __builtin_amdgcn_readlane(__builtin_bit_cast(int, m), 63));
            unsigned long long msk = __ballot(bd == bw);
            int wl  = (int)__builtin_ctzll(msk);
            int wbi = __builtin_amdgcn_readlane(bi, wl);
            int pw  = (w * 64 + wl) * 16 + wbi;
            unsigned long long key =
                ((unsigned long long)__builtin_bit_cast(unsigned, bw) << 32) |
                (unsigned long long)(unsigned)(4095 - pw);
            int par = s & 1;
            if (l == 0) sK[par * 4 + w] = key;
            __syncthreads();
            u64x2 kA = *(u64x2*)&sK[par * 4 + 0];
            u64x2 kB = *(u64x2*)&sK[par * 4 + 2];
            unsigned long long ka = kA[0] > kA[1] ? kA[0] : kA[1];
            unsigned long long kb = kB[0] > kB[1] ? kB[0] : kB[1];
            unsigned long long g  = ka > kb ? ka : kb;
            int p = 4095 - (int)(g & 0xFFFu);
            cx = px_s[p]; cy = py_s[p]; cz = pz_s[p];
        }
    } else {
        // ---------------- workers: WT prep + gated kNN + X build ----------------
        int wk = bid - 8;
        if (wk < 40) {
#pragma unroll
            for (int ch = 0; ch < 10; ch++) {
                int idx = (wk * 10 + ch) * 256 + t;
                if (idx < 13824) {
                    int row = idx / 96, k = idx % 96;
                    A.WT1[idx] = f2bf((k < 67 && row < 134) ? A.fc1_w[k * 134 + row] : 0.0f);
                } else if (idx < 26112) {
                    int j = idx - 13824;
                    int row = j / 96, k = j % 96;
                    A.WT1[13824 + j] = f2bf((k < 67) ? A.sc_w[k * 128 + row] : 0.0f);
                } else if (idx < 49152) {
                    int j = idx - 26112;
                    int row = j / 160, k = j % 160;
                    A.WT2[j] = f2bf((k < 134 && row < 134) ? A.fc2_w[k * 134 + row] : 0.0f);
                } else if (idx < 69632) {
                    int j = idx - 49152;
                    int row = j / 160, k = j % 160;
                    A.WT3[j] = f2bf((k < 134) ? A.fc3_w[k * 128 + row] : 0.0f);
                }
            }
        }
        float* sqnL = (float*)smem;            // 4096 f32 for my batch
        int* sNbr = (int*)(smem + 16384);      // [4][16]
        int b = wk & 7;                        // workers % 8 == 0 -> fixed batch
        const float* xb = A.xyz + (size_t)b * N_ * 3;
#pragma unroll
        for (int i = 0; i < 16; i++) {
            int p = i * 256 + t;
            float x = xb[p * 3 + 0], y = xb[p * 3 + 1], z = xb[p * 3 + 2];
            sqnL[p] = __fadd_rn(__fadd_rn(__fmul_rn(x, x), __fmul_rn(y, y)),
                                __fmul_rn(z, z));
        }
        __syncthreads();
        int w = t >> 6, l = t & 63;
        for (int G = wk; G < 2048; G += A.workers) {
            int sidx = (G >> 3) * 4 + w;       // this wave's query within batch
            int q = b * 1024 + sidx;
            while (__hip_atomic_load(A.wm + b * 16, __ATOMIC_ACQUIRE,
                                     __HIP_MEMORY_SCOPE_AGENT) <= sidx)
                __builtin_amdgcn_s_sleep(32);
            float qx = A.out[(size_t)q * 3 + 0];
            float qy = A.out[(size_t)q * 3 + 1];
            float qz = A.out[(size_t)q * 3 + 2];
            float sa = __fadd_rn(__fadd_rn(__fmul_rn(qx, qx), __fmul_rn(qy, qy)),
                                 __fmul_rn(qz, qz));
            float d16[16]; int i16[16];
#pragma unroll
            for (int j = 0; j < 16; j++) { d16[j] = 3.0e38f; i16[j] = -1; }
            for (int i = 0; i < N_ / 64; i++) {
                int n = i * 64 + l;
                float bx = xb[n * 3 + 0], by = xb[n * 3 + 1], bz = xb[n * 3 + 2];
                float dot = __fmaf_rn(qz, bz, __fmaf_rn(qy, by, __fmul_rn(qx, bx)));
                float d = __fsub_rn(__fadd_rn(sa, sqnL[n]), __fmul_rn(2.0f, dot));
                if (d < d16[0]) {
                    d16[0] = d; i16[0] = n;
#pragma unroll
                    for (int j = 0; j < 15; j++) {
                        if (d16[j] < d16[j + 1]) {
                            float td = d16[j]; d16[j] = d16[j + 1]; d16[j + 1] = td;
                            int   ti = i16[j]; i16[j] = i16[j + 1]; i16[j + 1] = ti;
                        }
                    }
                }
            }
#pragma unroll
            for (int r = 0; r < 16; r++) {
                float cd = d16[15]; int cn = i16[15];
#pragma unroll
                for (int off = 1; off < 64; off <<= 1) {
                    float od = __shfl_xor(cd, off);
                    int   on = __shfl_xor(cn, off);
                    if (od < cd || (od == cd && on < cn)) { cd = od; cn = on; }
                }
                if (l == 0) sNbr[w * 16 + r] = cn;
                if (i16[15] == cn) {
#pragma unroll
                    for (int j = 15; j >= 1; j--) { d16[j] = d16[j - 1]; i16[j] = i16[j - 1]; }
                    d16[0] = 3.0e38f; i16[0] = -1;
                }
            }
            __syncthreads();
            int row = l >> 2, seg = l & 3;
            int n = sNbr[w * 16 + row];
            const float* pr = A.pts + ((size_t)b * N_ + n) * CIN_;
            const float* xr = A.xyz + ((size_t)b * N_ + n) * 3;
            float v[24];
#pragma unroll
            for (int e = 0; e < 24; e++) {
                int c = seg * 24 + e;
                float val;
                if (c == 0)      val = xr[0] - qx;
                else if (c == 1) val = xr[1] - qy;
                else if (c == 2) val = xr[2] - qz;
                else if (c < 67) val = pr[c - 3];
                else             val = 0.0f;
                v[e] = val;
            }
            short8 s0 = pack8_bf16(v), s1 = pack8_bf16(v + 8), s2 = pack8_bf16(v + 16);
            unsigned short* xp = A.X + ((size_t)q * 16 + row) * 96 + seg * 24;
            *(short8*)xp = s0;
            *(short8*)(xp + 8) = s1;
            *(short8*)(xp + 16) = s2;
            __syncthreads();
        }
    }
    gridbar(A.bar_cnt, A.bar_gen, nblk, t);

    // ---------------- g1 / g2 / g3 ----------------
    {
        unsigned short* sBuf = (unsigned short*)smem;   // 21504 u16
        float* sSt = (float*)(smem + 43008);            // 288 f32
        float* sAC = (float*)(smem + 44160);            // 320 f32
        for (int tile = bid; tile < 2048; tile += nblk) {
            if (tile < 1024)
                gemm_core<96, 9, false>(A.X, A.WT1, A.Z1, bn1_sum, bn1_sq, 134,
                                        nullptr, nullptr, nullptr, nullptr,
                                        tile * 128, sBuf, sSt, sAC, t);
            else
                gemm_core<96, 8, false>(A.X, A.WT1 + 13824, A.ZSC, bnsc_sum, bnsc_sq, 128,
                                        nullptr, nullptr, nullptr, nullptr,
                                        (tile - 1024) * 128, sBuf, sSt, sAC, t);
        }
        gridbar(A.bar_cnt, A.bar_gen, nblk, t);
        for (int tile = bid; tile < 1024; tile += nblk)
            gemm_core<160, 9, true>(A.Z1, A.WT2, A.Z2, bn2_sum, bn2_sq, 134,
                                    bn1_sum, bn1_sq, A.bn1_g, A.bn1_b,
                                    tile * 128, sBuf, sSt, sAC, t);
        gridbar(A.bar_cnt, A.bar_gen, nblk, t);
        for (int tile = bid; tile < 1024; tile += nblk)
            gemm_core<160, 8, true>(A.Z2, A.WT3, A.Z1 /*=Z3*/, bn3_sum, bn3_sq, 128,
                                    bn2_sum, bn2_sq, A.bn2_g, A.bn2_b,
                                    tile * 128, sBuf, sSt, sAC, t);
        gridbar(A.bar_cnt, A.bar_gen, nblk, t);
    }

    // ---------------- final: bn3+bnsc, relu, max over K ----------------
    {
        float* sF = (float*)smem;   // 512 f32
        if (t < 128) {
            const float inv = 1.0f / (float)M_;
            float m3 = bn3_sum[t] * inv, v3 = bn3_sq[t] * inv - m3 * m3;
            float a3 = A.bn3_g[t] * rsqrtf(v3 + 1e-5f), c3 = A.bn3_b[t] - a3 * m3;
            float ms = bnsc_sum[t] * inv, vs = bnsc_sq[t] * inv - ms * ms;
            float as = A.scbn_g[t] * rsqrtf(vs + 1e-5f), cs = A.scbn_b[t] - as * ms;
            sF[t * 4 + 0] = a3; sF[t * 4 + 1] = c3; sF[t * 4 + 2] = as; sF[t * 4 + 3] = cs;
        }
        __syncthreads();
        for (int c = bid; c < 512; c += nblk) {
            int tid = c * 256 + t;
            int bs = tid >> 4, ch0 = (tid & 15) * 8;
            float A3[8], C3[8], AS[8], CS[8], mx[8];
#pragma unroll
            for (int e = 0; e < 8; e++) {
                f32x4 f = *(f32x4*)&sF[(ch0 + e) * 4];
                A3[e] = f[0]; C3[e] = f[1]; AS[e] = f[2]; CS[e] = f[3];
                mx[e] = 0.0f;
            }
            const unsigned short* z3p = A.Z1 + (size_t)bs * 16 * 128 + ch0;
            const unsigned short* zsp = A.ZSC + (size_t)bs * 16 * 128 + ch0;
#pragma unroll
            for (int k = 0; k < 16; k++) {
                short8 z3 = *(const short8*)(z3p + (size_t)k * 128);
                short8 zs = *(const short8*)(zsp + (size_t)k * 128);
#pragma unroll
                for (int e = 0; e < 8; e++) {
                    float y = fmaxf(A3[e] * bf2f((unsigned short)z3[e]) + C3[e]
                                    + AS[e] * bf2f((unsigned short)zs[e]) + CS[e], 0.0f);
                    mx[e] = fmaxf(mx[e], y);
                }
            }
            float* op = A.out + 24576 + (size_t)bs * 128 + ch0;
#pragma unroll
            for (int e = 0; e < 8; e++) op[e] = mx[e];
        }
    }
}

// =====================================================================
// Fallback kernels (R6 structure) — used if cooperative launch fails.
// =====================================================================
__global__ __launch_bounds__(256) void fps_aux_kernel(
    const float* __restrict__ xyz, float* __restrict__ outxyz,
    const float* __restrict__ fc1_w, const float* __restrict__ sc_w,
    const float* __restrict__ fc2_w, const float* __restrict__ fc3_w,
    unsigned short* __restrict__ WT1, unsigned short* __restrict__ WT2,
    unsigned short* __restrict__ WT3, float* __restrict__ sqn)
{
    __shared__ float px_s[N_], py_s[N_], pz_s[N_];
    __shared__ float sOut[S_ * 3];
    __shared__ __attribute__((aligned(16))) unsigned long long sK[2][4];
    int t = threadIdx.x;
    if (blockIdx.x >= 8) {
        int aux = blockIdx.x - 8;
#pragma unroll
        for (int ch = 0; ch < 10; ch++) {
            int idx = (aux * 10 + ch) * 256 + t;
            if (idx < 13824) {
                int row = idx / 96, k = idx % 96;
                WT1[idx] = f2bf((k < 67 && row < 134) ? fc1_w[k * 134 + row] : 0.0f);
            } else if (idx < 26112) {
                int j = idx - 13824;
                int row = j / 96, k = j % 96;
                WT1[13824 + j] = f2bf((k < 67) ? sc_w[k * 128 + row] : 0.0f);
            } else if (idx < 49152) {
                int j = idx - 26112;
                int row = j / 160, k = j % 160;
                WT2[j] = f2bf((k < 134 && row < 134) ? fc2_w[k * 134 + row] : 0.0f);
            } else if (idx < 69632) {
                int j = idx - 49152;
                int row = j / 160, k = j % 160;
                WT3[j] = f2bf((k < 134) ? fc3_w[k * 128 + row] : 0.0f);
            } else {
                int i = idx - 69632;
                float x = xyz[i * 3 + 0], y = xyz[i * 3 + 1], z = xyz[i * 3 + 2];
                sqn[i] = __fadd_rn(__fadd_rn(__fmul_rn(x, x), __fmul_rn(y, y)),
                                   __fmul_rn(z, z));
            }
        }
        return;
    }
    int b = blockIdx.x;
    const float* xb = xyz + (size_t)b * N_ * 3;
    int w = t >> 6, l = t & 63;
    float px[16], py[16], pz[16], dst[16];
    {
        float flat[48];
        const float4* xb4 = (const float4*)xb + t * 12;
#pragma unroll
        for (int j = 0; j < 12; j++) {
            float4 v = xb4[j];
            flat[j * 4 + 0] = v.x; flat[j * 4 + 1] = v.y;
            flat[j * 4 + 2] = v.z; flat[j * 4 + 3] = v.w;
        }
#pragma unroll
        for (int i = 0; i < 16; i++) {
            int p = t * 16 + i;
            px[i] = flat[i * 3 + 0]; py[i] = flat[i * 3 + 1]; pz[i] = flat[i * 3 + 2];
            dst[i] = 1e10f;
            px_s[p] = px[i]; py_s[p] = py[i]; pz_s[p] = pz[i];
            asm volatile("" : "+v"(px[i]), "+v"(py[i]), "+v"(pz[i]));
        }
    }
    __syncthreads();
    float cx = px_s[0], cy = py_s[0], cz = pz_s[0];
    for (int s = 0; s < S_; s++) {
        if (t == 0) { sOut[s * 3 + 0] = cx; sOut[s * 3 + 1] = cy; sOut[s * 3 + 2] = cz; }
        if (s == S_ - 1) break;
        float bd = -1.0f; int bi = 0;
#pragma unroll
        for (int i = 0; i < 16; i++) {
            float dx = __fsub_rn(px[i], cx);
            float dy = __fsub_rn(py[i], cy);
            float dz = __fsub_rn(pz[i], cz);
            float d  = __fadd_rn(__fadd_rn(__fmul_rn(dx, dx), __fmul_rn(dy, dy)),
                                 __fmul_rn(dz, dz));
            float nd = fminf(dst[i], d);
            dst[i] = nd;
            if (nd > bd) bi = i;
            bd = fmaxf(bd, nd);
        }
        float m = bd;
        m = dpp_maxf<0xB1>(m); m = dpp_maxf<0x4E>(m); m = dpp_maxf<0x141>(m);
        m = dpp_maxf<0x140>(m); m = dpp_maxf<0x142>(m); m = dpp_maxf<0x143>(m);
        float bw = __builtin_bit_cast(float,
                       __builtin_amdgcn_readlane(__builtin_bit_cast(int, m), 63));
        unsigned long long msk = __ballot(bd == bw);
        int wl  = (int)__builtin_ctzll(msk);
        int wbi = __builtin_amdgcn_readlane(bi, wl);
        int pw  = (w * 64 + wl) * 16 + wbi;
        unsigned long long key =
            ((unsigned long long)__builtin_bit_cast(unsigned, bw) << 32) |
            (unsigned long long)(unsigned)(4095 - pw);
        int par = s & 1;
        if (l == 0) sK[par][w] = key;
        __syncthreads();
        u64x2 kA = *(u64x2*)&sK[par][0];
        u64x2 kB = *(u64x2*)&sK[par][2];
        unsigned long long ka = kA[0] > kA[1] ? kA[0] : kA[1];
        unsigned long long kb = kB[0] > kB[1] ? kB[0] : kB[1];
        unsigned long long g  = ka > kb ? ka : kb;
        int p = 4095 - (int)(g & 0xFFFu);
        cx = px_s[p]; cy = py_s[p]; cz = pz_s[p];
    }
    __syncthreads();
    float* ob = outxyz + (size_t)b * S_ * 3;
    for (int i = t; i < S_ * 3; i += 256) ob[i] = sOut[i];
}

__global__ __launch_bounds__(256) void knn_build(const float* __restrict__ xyz,
                                                 const float* __restrict__ sqn,
                                                 const float* __restrict__ newxyz,
                                                 const float* __restrict__ pts,
                                                 unsigned short* __restrict__ X)
{
    __shared__ int sNbr[4][16];
    int w = threadIdx.x >> 6, l = threadIdx.x & 63;
    int q = blockIdx.x * 4 + w;
    int b = q >> 10;
    const float* xb = xyz + (size_t)b * N_ * 3;
    const float* sb = sqn + (size_t)b * N_;
    float qx = newxyz[(size_t)q * 3 + 0];
    float qy = newxyz[(size_t)q * 3 + 1];
    float qz = newxyz[(size_t)q * 3 + 2];
    float sa = __fadd_rn(__fadd_rn(__fmul_rn(qx, qx), __fmul_rn(qy, qy)), __fmul_rn(qz, qz));
    float d16[16]; int i16[16];
#pragma unroll
    for (int j = 0; j < 16; j++) { d16[j] = 3.0e38f; i16[j] = -1; }
    for (int i = 0; i < N_ / 64; i++) {
        int n = i * 64 + l;
        float bx = xb[n * 3 + 0], by = xb[n * 3 + 1], bz = xb[n * 3 + 2];
        float dot = __fmaf_rn(qz, bz, __fmaf_rn(qy, by, __fmul_rn(qx, bx)));
        float d = __fsub_rn(__fadd_rn(sa, sb[n]), __fmul_rn(2.0f, dot));
        if (d < d16[0]) {
            d16[0] = d; i16[0] = n;
#pragma unroll
            for (int j = 0; j < 15; j++) {
                if (d16[j] < d16[j + 1]) {
                    float td = d16[j]; d16[j] = d16[j + 1]; d16[j + 1] = td;
                    int   ti = i16[j]; i16[j] = i16[j + 1]; i16[j + 1] = ti;
                }
            }
        }
    }
#pragma unroll
    for (int r = 0; r < 16; r++) {
        float cd = d16[15]; int cn = i16[15];
#pragma unroll
        for (int off = 1; off < 64; off <<= 1) {
            float od = __shfl_xor(cd, off);
            int   on = __shfl_xor(cn, off);
            if (od < cd || (od == cd && on < cn)) { cd = od; cn = on; }
        }
        if (l == 0) sNbr[w][r] = cn;
        if (i16[15] == cn) {
#pragma unroll
            for (int j = 15; j >= 1; j--) { d16[j] = d16[j - 1]; i16[j] = i16[j - 1]; }
            d16[0] = 3.0e38f; i16[0] = -1;
        }
    }
    __syncthreads();
    int row = l >> 2, seg = l & 3;
    int n = sNbr[w][row];
    const float* pr = pts + ((size_t)b * N_ + n) * CIN_;
    const float* xr = xyz + ((size_t)b * N_ + n) * 3;
    float v[24];
#pragma unroll
    for (int e = 0; e < 24; e++) {
        int c = seg * 24 + e;
        float val;
        if (c == 0)      val = xr[0] - qx;
        else if (c == 1) val = xr[1] - qy;
        else if (c == 2) val = xr[2] - qz;
        else if (c < 67) val = pr[c - 3];
        else             val = 0.0f;
        v[e] = val;
    }
    short8 s0 = pack8_bf16(v), s1 = pack8_bf16(v + 8), s2 = pack8_bf16(v + 16);
    unsigned short* xp = X + ((size_t)q * 16 + row) * 96 + seg * 24;
    *(short8*)xp = s0;
    *(short8*)(xp + 8) = s1;
    *(short8*)(xp + 16) = s2;
}

__global__ __launch_bounds__(256) void gemm1_fused(
    const unsigned short* __restrict__ X, const unsigned short* __restrict__ WT1,
    unsigned short* __restrict__ Z1, unsigned short* __restrict__ ZSC,
    float* s1, float* q1, float* ssc, float* qsc)
{
    __shared__ unsigned short sBuf[21504];
    __shared__ float sSt[288];
    __shared__ float sAC[320];
    int t = threadIdx.x;
    if (blockIdx.x < 1024)
        gemm_core<96, 9, false>(X, WT1, Z1, s1, q1, 134,
                                nullptr, nullptr, nullptr, nullptr,
                                blockIdx.x * 128, sBuf, sSt, sAC, t);
    else
        gemm_core<96, 8, false>(X, WT1 + 13824, ZSC, ssc, qsc, 128,
                                nullptr, nullptr, nullptr, nullptr,
                                (blockIdx.x - 1024) * 128, sBuf, sSt, sAC, t);
}

__global__ __launch_bounds__(256) void gemm_l2(
    const unsigned short* __restrict__ Zin, const unsigned short* __restrict__ WT,
    unsigned short* __restrict__ Zout, float* sum, float* sq,
    const float* ps, const float* pq, const float* pg, const float* pb)
{
    __shared__ unsigned short sBuf[21504];
    __shared__ float sSt[288];
    __shared__ float sAC[320];
    gemm_core<160, 9, true>(Zin, WT, Zout, sum, sq, 134, ps, pq, pg, pb,
                            blockIdx.x * 128, sBuf, sSt, sAC, threadIdx.x);
}

__global__ __launch_bounds__(256) void gemm_l3(
    const unsigned short* __restrict__ Zin, const unsigned short* __restrict__ WT,
    unsigned short* __restrict__ Zout, float* sum, float* sq,
    const float* ps, const float* pq, const float* pg, const float* pb)
{
    __shared__ unsigned short sBuf[21504];
    __shared__ float sSt[288];
    __shared__ float sAC[320];
    gemm_core<160, 8, true>(Zin, WT, Zout, sum, sq, 128, ps, pq, pg, pb,
                            blockIdx.x * 128, sBuf, sSt, sAC, threadIdx.x);
}

__global__ __launch_bounds__(256) void final_kernel(
    const unsigned short* __restrict__ Z3, const unsigned short* __restrict__ ZSC,
    const float* __restrict__ sum3, const float* __restrict__ sq3,
    const float* __restrict__ g3, const float* __restrict__ b3,
    const float* __restrict__ sumsc, const float* __restrict__ sqsc,
    const float* __restrict__ gsc, const float* __restrict__ bsc,
    float* __restrict__ out)
{
    __shared__ float sF[512];
    int t = threadIdx.x;
    if (t < 128) {
        const float inv = 1.0f / (float)M_;
        float m3 = sum3[t] * inv, v3 = sq3[t] * inv - m3 * m3;
        float a3 = g3[t] * rsqrtf(v3 + 1e-5f), c3 = b3[t] - a3 * m3;
        float ms = sumsc[t] * inv, vs = sqsc[t] * inv - ms * ms;
        float as = gsc[t] * rsqrtf(vs + 1e-5f), cs = bsc[t] - as * ms;
        sF[t * 4 + 0] = a3; sF[t * 4 + 1] = c3; sF[t * 4 + 2] = as; sF[t * 4 + 3] = cs;
    }
    __syncthreads();
    int tid = blockIdx.x * 256 + t;
    int bs = tid >> 4, ch0 = (tid & 15) * 8;
    float A3[8], C3[8], AS[8], CS[8], mx[8];
#pragma unroll
    for (int e = 0; e < 8; e++) {
        f32x4 f = *(f32x4*)&sF[(ch0 + e) * 4];
        A3[e] = f[0]; C3[e] = f[1]; AS[e] = f[2]; CS[e] = f[3];
        mx[e] = 0.0f;
    }
    const unsigned short* z3p = Z3 + (size_t)bs * 16 * 128 + ch0;
    const unsigned short* zsp = ZSC + (size_t)bs * 16 * 128 + ch0;
#pragma unroll
    for (int k = 0; k < 16; k++) {
        short8 z3 = *(const short8*)(z3p + (size_t)k * 128);
        short8 zs = *(const short8*)(zsp + (size_t)k * 128);
#pragma unroll
        for (int e = 0; e < 8; e++) {
            float y = fmaxf(A3[e] * bf2f((unsigned short)z3[e]) + C3[e]
                            + AS[e] * bf2f((unsigned short)zs[e]) + CS[e], 0.0f);
            mx[e] = fmaxf(mx[e], y);
        }
    }
    float* op = out + 24576 + (size_t)bs * 128 + ch0;
#pragma unroll
    for (int e = 0; e < 8; e++) op[e] = mx[e];
}

// ---------------- workspace layout (bytes) ----------------
#define WS_STATS 0           /* 1056 f32 stats */
#define WS_WM    4224        /* 8 x 16 ints (cacheline-spread watermarks) */
#define WS_BCNT  4736
#define WS_BGEN  4800
#define WS_WT1   8192
#define WS_WT2   61440
#define WS_WT3   108544
#define WS_SQN   149760
#define WS_X     281088
#define WS_Z1    25447424
#define WS_ZSC   63196416
#define WS_Z2    96751104

extern "C" void kernel_launch(void* const* d_in, const int* in_sizes, int n_in,
                              void* d_out, int out_size, void* d_ws, size_t ws_size,
                              hipStream_t stream)
{
    const float* xyz    = (const float*)d_in[0];
    const float* pts    = (const float*)d_in[1];
    const float* fc1_w  = (const float*)d_in[2];
    const float* bn1_g  = (const float*)d_in[4];
    const float* bn1_b  = (const float*)d_in[5];
    const float* fc2_w  = (const float*)d_in[6];
    const float* bn2_g  = (const float*)d_in[8];
    const float* bn2_b  = (const float*)d_in[9];
    const float* fc3_w  = (const float*)d_in[10];
    const float* bn3_g  = (const float*)d_in[12];
    const float* bn3_b  = (const float*)d_in[13];
    const float* sc_w   = (const float*)d_in[14];
    const float* scbn_g = (const float*)d_in[16];
    const float* scbn_b = (const float*)d_in[17];

    char* ws = (char*)d_ws;
    float* st = (float*)(ws + WS_STATS);
    float* bn1_sum = st + 0,    *bn1_sq = st + 136;
    float* bnsc_sum = st + 272, *bnsc_sq = st + 400;
    float* bn2_sum = st + 528,  *bn2_sq = st + 664;
    float* bn3_sum = st + 800,  *bn3_sq = st + 928;

    unsigned short* WT1 = (unsigned short*)(ws + WS_WT1);
    unsigned short* WT2 = (unsigned short*)(ws + WS_WT2);
    unsigned short* WT3 = (unsigned short*)(ws + WS_WT3);
    float* SQN = (float*)(ws + WS_SQN);
    unsigned short* X   = (unsigned short*)(ws + WS_X);
    unsigned short* Z1  = (unsigned short*)(ws + WS_Z1);
    unsigned short* ZSC = (unsigned short*)(ws + WS_ZSC);
    unsigned short* Z2  = (unsigned short*)(ws + WS_Z2);
    float* out = (float*)d_out;

    hipMemsetAsync(ws, 0, 4864, stream);   // stats + watermarks + barrier state

    int occ = 0;
    bool launched = false;
    if (hipOccupancyMaxActiveBlocksPerMultiprocessor(&occ, mega, 256, 0) == hipSuccess
        && occ > 0) {
        int blocks = occ * 256;
        if (blocks > 512) blocks = 512;
        int workers = ((blocks - 8) / 8) * 8;
        if (workers >= 40) {
            MegaArgs ma;
            ma.xyz = xyz; ma.pts = pts; ma.fc1_w = fc1_w; ma.sc_w = sc_w;
            ma.fc2_w = fc2_w; ma.fc3_w = fc3_w;
            ma.bn1_g = bn1_g; ma.bn1_b = bn1_b; ma.bn2_g = bn2_g; ma.bn2_b = bn2_b;
            ma.bn3_g = bn3_g; ma.bn3_b = bn3_b; ma.scbn_g = scbn_g; ma.scbn_b = scbn_b;
            ma.WT1 = WT1; ma.WT2 = WT2; ma.WT3 = WT3; ma.SQN = SQN;
            ma.X = X; ma.Z1 = Z1; ma.ZSC = ZSC; ma.Z2 = Z2;
            ma.st = st; ma.wm = (int*)(ws + WS_WM);
            ma.bar_cnt = (int*)(ws + WS_BCNT); ma.bar_gen = (int*)(ws + WS_BGEN);
            ma.out = out; ma.workers = workers;
            void* kargs[] = { &ma };
            launched = (hipLaunchCooperativeKernel((const void*)mega,
                            dim3(workers + 8), dim3(256), kargs, 0, stream) == hipSuccess);
        }
    }
    if (!launched) {
        // fallback: R6 multi-kernel path
        fps_aux_kernel<<<48, 256, 0, stream>>>(xyz, out, fc1_w, sc_w, fc2_w, fc3_w,
                                               WT1, WT2, WT3, SQN);
        knn_build<<<2048, 256, 0, stream>>>(xyz, SQN, out, pts, X);
        gemm1_fused<<<2048, 256, 0, stream>>>(X, WT1, Z1, ZSC,
                                              bn1_sum, bn1_sq, bnsc_sum, bnsc_sq);
        gemm_l2<<<1024, 256, 0, stream>>>(Z1, WT2, Z2, bn2_sum, bn2_sq,
                                          bn1_sum, bn1_sq, bn1_g, bn1_b);
        gemm_l3<<<1024, 256, 0, stream>>>(Z2, WT3, Z1, bn3_sum, bn3_sq,
                                          bn2_sum, bn2_sq, bn2_g, bn2_b);
        final_kernel<<<512, 256, 0, stream>>>(Z1, ZSC, bn3_sum, bn3_sq, bn3_g, bn3_b,
                                              bnsc_sum, bnsc_sq, scbn_g, scbn_b, out);
    }
}